// Round 3
// baseline (431.572 us; speedup 1.0000x reference)
//
#include <hip/hip_runtime.h>

// Dims (fixed by the reference)
#define NN 1024
// K padded: 64 (ns) + 3 (coords) + 1 (bias) = 68 -> pad to 96 = 3 x 32
#define KP 96
#define LSTR 104   // LDS row stride in shorts for A-tile

typedef __attribute__((ext_vector_type(8))) short short8;
typedef __attribute__((ext_vector_type(4))) short short4v;
typedef __attribute__((ext_vector_type(4))) float f32x4;

__device__ __forceinline__ short f2bf(float f){
  unsigned u = __builtin_bit_cast(unsigned, f);
  u += 0x7FFFu + ((u >> 16) & 1u);       // RNE
  return (short)(u >> 16);
}

// ---------------- K1: fused prep (PT Gram + B panel + V panel) -------------
// blocks 0..31  : PT[h][kk][c] (bf16) = sum_d Wq[h*1024+d][c] * X[d][kk]
//                 h = bz>>2, kk-quarter kq = bz&3 (24 kk each)
// blocks 32..95 : B panel Bm[b][m][kk] (bf16)
// blocks 96..223: V panel Vm[h*1024+d][kk] (bf16)
__global__ __launch_bounds__(256) void prep_all(
    const float* __restrict__ Wq, const float* __restrict__ Wk,
    const float* __restrict__ Wlq, const float* __restrict__ blq,
    const float* __restrict__ Wv, const float* __restrict__ Wlv,
    const float* __restrict__ blv, const float* __restrict__ ns,
    const float* __restrict__ coord,
    short* __restrict__ PT, short* __restrict__ Bm, short* __restrict__ Vm){
  const int bz = blockIdx.x, t = threadIdx.x;
  if (bz < 32){
    __shared__ float red[4][64][24];                    // 24.6 KB
    int h = bz >> 2, kq = bz & 3;
    int c = t & 63, p = t >> 6;                         // p: d-quarter
    float acc[24];
    #pragma unroll
    for (int j = 0; j < 24; ++j) acc[j] = 0.f;
    for (int i = 0; i < 256; ++i){
      int o = h * 1024 + p * 256 + i;
      float wq = Wq[o * 64 + c];                        // coalesced over c
      #pragma unroll
      for (int j = 0; j < 24; ++j){
        int kk = kq * 24 + j;                           // wave-uniform
        float bv;
        if (kk < 64)        bv = Wk[o * 64 + kk];
        else if (kk < 67)   bv = Wlq[o * 3 + (kk - 64)];
        else if (kk == 67)  bv = blq[o];
        else                bv = 0.f;
        acc[j] += wq * bv;
      }
    }
    #pragma unroll
    for (int j = 0; j < 24; ++j) red[p][c][j] = acc[j];
    __syncthreads();
    if (p == 0){
      #pragma unroll
      for (int j = 0; j < 24; ++j){
        float s = red[0][c][j] + red[1][c][j] + red[2][c][j] + red[3][c][j];
        PT[(h * KP + kq * 24 + j) * 64 + c] = f2bf(s);
      }
    }
  } else if (bz < 96){
    __shared__ float nsT[64][65];
    __shared__ float cst[3][64];
    int idx0 = bz - 32, b = idx0 >> 4, m0 = (idx0 & 15) * 64;
    #pragma unroll
    for (int it = 0; it < 16; ++it){
      int idx = it * 256 + t;
      int c = idx >> 6, mm = idx & 63;
      nsT[mm][c] = ns[(b * 64 + c) * NN + m0 + mm];     // coalesced over mm
    }
    if (t < 192){
      int j = t >> 6, mm = t & 63;
      cst[j][mm] = coord[(b * 3 + j) * NN + m0 + mm];
    }
    __syncthreads();
    #pragma unroll
    for (int it = 0; it < 24; ++it){
      int idx = it * 256 + t;                           // 64*96 = 6144
      int mm = idx / KP, kk = idx - mm * KP;
      float v = (kk < 64) ? nsT[mm][kk]
              : (kk < 67) ? cst[kk - 64][mm]
              : (kk == 67) ? 1.f : 0.f;
      Bm[(b * NN + m0 + mm) * KP + kk] = f2bf(v);
    }
  } else {
    int o0 = (bz - 96) * 64;
    #pragma unroll
    for (int it = 0; it < 24; ++it){
      int idx = it * 256 + t;
      int r = idx / KP, kk = idx - r * KP;
      int o = o0 + r;
      float v = (kk < 64) ? Wv[o * 64 + kk]
              : (kk < 67) ? Wlv[o * 3 + (kk - 64)]
              : (kk == 67) ? blv[o] : 0.f;
      Vm[o * KP + kk] = f2bf(v);
    }
  }
}

// ---------------- K2: fused attention, P held in registers ----------------
// Per WG: (b,h, 32-row n-block), 4 waves; wave owns an m/d QUARTER (256).
// Key identity: pass-2 lane mapping (i=q*4+r, j=ln) at d-chunk ds equals
// pass-1's at m-chunk ms=ds -> each lane's attention weights in pass 2 are
// exactly the exp values it computed in pass 1. Keep them packed bf16 in
// 64 VGPRs; no energy recompute, no second exp, no LDS P.
__global__ __launch_bounds__(256) void attn_main(
    const float* __restrict__ xs, const short* __restrict__ PT,
    const short* __restrict__ Bmat, const short* __restrict__ Vm,
    float* __restrict__ out){
  __shared__ short xsL[64 * 32];        // bf16 [c][n_local]  (4 KB)
  __shared__ short AL[32 * LSTR];       // bf16 A rows [n_local][kk] (6.5 KB)
  __shared__ float redS[32 * 4];        // per-row partial sums x 4 waves
  const int t = threadIdx.x, w = t >> 6, lane = t & 63;
  const int q = lane >> 4, ln = lane & 15;
  const int blk = blockIdx.x, nb = blk & 31, bh = blk >> 5;
  const int b = bh >> 3, h = bh & 7;
  const int n0 = nb * 32;

  // ---- stage xs[b][0..63][n0..n0+31] as bf16 ----
  const float* xsb = xs + b * 64 * NN;
  #pragma unroll
  for (int it = 0; it < 2; ++it){
    int idx = it * 256 + t;                     // 512 float4 units
    int c = idx >> 3, nn4 = (idx & 7) << 2;
    f32x4 v = *(const f32x4*)(xsb + c * NN + n0 + nn4);
    short4v pk;
    #pragma unroll
    for (int j = 0; j < 4; ++j) pk[j] = f2bf(v[j]);
    *(short4v*)(&xsL[c * 32 + nn4]) = pk;
  }
  __syncthreads();

  // ---- build A rows via MFMA: A = xs^T . PT^T ----
  // wave w: row-half rh = w&1, kt in {w>>1, w>>1+2, w>>1+4}
  const int rh = w & 1;
  short8 xf0, xf1;
  #pragma unroll
  for (int j = 0; j < 8; ++j){
    xf0[j] = xsL[(q * 8 + j) * 32 + rh * 16 + ln];
    xf1[j] = xsL[(32 + q * 8 + j) * 32 + rh * 16 + ln];
  }
  const short* PTh = PT + h * KP * 64;
  #pragma unroll
  for (int jt = 0; jt < 3; ++jt){
    int kt = (w >> 1) + 2 * jt;
    const short* pr = PTh + (kt * 16 + ln) * 64;
    short8 p0 = *(const short8*)(pr + q * 8);
    short8 p1 = *(const short8*)(pr + 32 + q * 8);
    f32x4 a = {0.f, 0.f, 0.f, 0.f};
    a = __builtin_amdgcn_mfma_f32_16x16x32_bf16(xf0, p0, a, 0, 0, 0);
    a = __builtin_amdgcn_mfma_f32_16x16x32_bf16(xf1, p1, a, 0, 0, 0);
    #pragma unroll
    for (int r = 0; r < 4; ++r)
      AL[(rh * 16 + q * 4 + r) * LSTR + kt * 16 + ln] = f2bf(a[r]);
  }
  __syncthreads();

  // ---- persistent fragments: all 32 rows ----
  short8 af[2][3], bn[2][3];
  const short* Bb = Bmat + b * NN * KP;
  #pragma unroll
  for (int rf = 0; rf < 2; ++rf){
    #pragma unroll
    for (int s = 0; s < 3; ++s){
      af[rf][s] = *(const short8*)(&AL[(rf * 16 + ln) * LSTR + s * 32 + q * 8]);
      bn[rf][s] = *(const short8*)(Bb + (n0 + rf * 16 + ln) * KP + s * 32 + q * 8);
    }
  }
  const float KEXP = 0.045084220f;   // log2(e)/32  (SCALE = sqrt(1024) = 32)

  // ---- pass 1: wave's m-quarter; keep exp values packed in registers ----
  float sum[2][4];
  #pragma unroll
  for (int rf = 0; rf < 2; ++rf)
    #pragma unroll
    for (int r = 0; r < 4; ++r) sum[rf][r] = 0.f;
  unsigned pw[2][4][8];              // packed bf16 pairs over ms

  #pragma unroll
  for (int ms = 0; ms < 16; ++ms){
    const short* bp = Bb + (w * 256 + ms * 16 + ln) * KP + q * 8;
    short8 bf0 = *(const short8*)(bp);
    short8 bf1 = *(const short8*)(bp + 32);
    short8 bf2 = *(const short8*)(bp + 64);
    #pragma unroll
    for (int rf = 0; rf < 2; ++rf){
      f32x4 e = {0.f, 0.f, 0.f, 0.f};
      e = __builtin_amdgcn_mfma_f32_16x16x32_bf16(af[rf][0], bf0, e, 0, 0, 0);
      e = __builtin_amdgcn_mfma_f32_16x16x32_bf16(af[rf][1], bf1, e, 0, 0, 0);
      e = __builtin_amdgcn_mfma_f32_16x16x32_bf16(af[rf][2], bf2, e, 0, 0, 0);
      #pragma unroll
      for (int r = 0; r < 4; ++r){
        float pe = __builtin_amdgcn_exp2f(e[r] * KEXP);
        sum[rf][r] += pe;
        unsigned hb = (unsigned)(unsigned short)f2bf(pe);
        if (ms & 1) pw[rf][r][ms >> 1] |= hb << 16;
        else        pw[rf][r][ms >> 1]  = hb;
      }
    }
  }
  // reduce over the 16 m-columns (ln bits), then across waves via LDS
  #pragma unroll
  for (int rf = 0; rf < 2; ++rf){
    #pragma unroll
    for (int r = 0; r < 4; ++r){
      float s = sum[rf][r];
      s += __shfl_xor(s, 1); s += __shfl_xor(s, 2);
      s += __shfl_xor(s, 4); s += __shfl_xor(s, 8);
      if (ln == 0) redS[(rf * 16 + q * 4 + r) * 4 + w] = s;
    }
  }
  __syncthreads();
  float rinv[2][4];
  #pragma unroll
  for (int rf = 0; rf < 2; ++rf){
    #pragma unroll
    for (int r = 0; r < 4; ++r){
      f32x4 v4 = *(const f32x4*)(&redS[(rf * 16 + q * 4 + r) * 4]);
      rinv[rf][r] = 1.0f / (v4[0] + v4[1] + v4[2] + v4[3]);
    }
  }

  // ---- pass 2: wave's d-quarter: vc GEMM + cached P + store ----
  float* outp = out + (size_t)bh * (1024 * 1024);
  const short* Vh = Vm + h * 1024 * KP;
  #pragma unroll
  for (int ds = 0; ds < 16; ++ds){
    const short* vp = Vh + (w * 256 + ds * 16 + ln) * KP + q * 8;
    short8 vf0 = *(const short8*)(vp);
    short8 vf1 = *(const short8*)(vp + 32);
    short8 vf2 = *(const short8*)(vp + 64);
    #pragma unroll
    for (int rf = 0; rf < 2; ++rf){
      f32x4 vv = {0.f, 0.f, 0.f, 0.f};
      vv = __builtin_amdgcn_mfma_f32_16x16x32_bf16(bn[rf][0], vf0, vv, 0, 0, 0);
      vv = __builtin_amdgcn_mfma_f32_16x16x32_bf16(bn[rf][1], vf1, vv, 0, 0, 0);
      vv = __builtin_amdgcn_mfma_f32_16x16x32_bf16(bn[rf][2], vf2, vv, 0, 0, 0);
      f32x4 o;
      #pragma unroll
      for (int r = 0; r < 4; ++r){
        unsigned u = pw[rf][r][ds >> 1];
        float pf = __builtin_bit_cast(float,
            (ds & 1) ? (u & 0xFFFF0000u) : (u << 16));
        o[r] = pf * rinv[rf][r] * vv[r];
      }
      // out[((b*8+h)*1024 + d)*1024 + n]
      *(f32x4*)(outp + (w * 256 + ds * 16 + ln) * NN + n0 + rf * 16 + q * 4) = o;
    }
  }
}

extern "C" void kernel_launch(void* const* d_in, const int* in_sizes, int n_in,
                              void* d_out, int out_size, void* d_ws, size_t ws_size,
                              hipStream_t stream){
  const float* coord = (const float*)d_in[0];
  const float* x     = (const float*)d_in[1];
  const float* nbr   = (const float*)d_in[2];
  const float* Wq    = (const float*)d_in[3];
  const float* Wk    = (const float*)d_in[4];
  const float* Wv    = (const float*)d_in[5];
  const float* Wlq   = (const float*)d_in[6];
  const float* blq   = (const float*)d_in[7];
  const float* Wlv   = (const float*)d_in[8];
  const float* blv   = (const float*)d_in[9];
  float* out = (float*)d_out;

  char* ws = (char*)d_ws;
  short* PT = (short*)ws;                         // 8*96*64*2   =   98304 B
  short* Bm = (short*)(ws + 98304);               // 4*1024*96*2 =  786432 B
  short* Vm = (short*)(ws + 98304 + 786432);      // 8*1024*96*2 = 1572864 B
  // total ws: 2,457,600 B

  prep_all<<<224,  256, 0, stream>>>(Wq, Wk, Wlq, blq, Wv, Wlv, blv, nbr, coord,
                                     PT, Bm, Vm);
  attn_main<<<1024, 256, 0, stream>>>(x, PT, Bm, Vm, out);
}

// Round 4
// 267.179 us; speedup vs baseline: 1.6153x; 1.6153x over previous
//
#include <hip/hip_runtime.h>

// Dims (fixed by the reference)
#define NN 1024
// K padded: 64 (ns) + 3 (coords) + 1 (bias) = 68 -> pad to 96 = 3 x 32
#define KP 96
#define LSTR 104   // LDS row stride in shorts for A-tile

typedef __attribute__((ext_vector_type(8))) short short8;
typedef __attribute__((ext_vector_type(4))) short short4v;
typedef __attribute__((ext_vector_type(4))) float f32x4;

__device__ __forceinline__ short f2bf(float f){
  unsigned u = __builtin_bit_cast(unsigned, f);
  u += 0x7FFFu + ((u >> 16) & 1u);       // RNE
  return (short)(u >> 16);
}

// ---------------- K1: fused prep -------------------------------------------
// blocks 0..287  : PT Gram (fp32 atomicAdd). 8 h x 9 kc (8 kk each) x 4 dz.
//                  PTf[h][kk][c] += sum_{d in dz-quarter} Wq[h*1024+d][c]*X[d][kk]
//                  (kk chunks >= 72 are all-pad -> omitted; memset provides 0)
// blocks 288..351: B panel Bm[b][m][kk] (bf16), waves 0..3 only
// blocks 352..479: V panel Vm[h*1024+d][kk] (bf16), waves 0..3 only
__global__ __launch_bounds__(1024) void prep_all(
    const float* __restrict__ Wq, const float* __restrict__ Wk,
    const float* __restrict__ Wlq, const float* __restrict__ blq,
    const float* __restrict__ Wv, const float* __restrict__ Wlv,
    const float* __restrict__ blv, const float* __restrict__ ns,
    const float* __restrict__ coord,
    float* __restrict__ PTf, short* __restrict__ Bm, short* __restrict__ Vm){
  const int bz = blockIdx.x, t = threadIdx.x;
  if (bz < 288){
    // ---- PT Gram: 16 iters x 9 loads per thread (proven-fast shape) ----
    __shared__ float red[16][64][8];                    // 32 KB
    int h = bz / 36, rem = bz - h * 36;
    int kc = rem >> 2, dz = rem & 3;                    // kc: 0..8, dz: 0..3
    int c = t & 63, p = t >> 6;                         // p: 0..15
    float acc[8];
    #pragma unroll
    for (int j = 0; j < 8; ++j) acc[j] = 0.f;
    #pragma unroll
    for (int i = 0; i < 16; ++i){
      int o = h * 1024 + dz * 256 + p * 16 + i;
      float wq = Wq[o * 64 + c];                        // coalesced over c
      #pragma unroll
      for (int j = 0; j < 8; ++j){
        int kk = kc * 8 + j;
        float bv;
        if (kk < 64)        bv = Wk[o * 64 + kk];
        else if (kk < 67)   bv = Wlq[o * 3 + (kk - 64)];
        else if (kk == 67)  bv = blq[o];
        else                bv = 0.f;
        acc[j] += wq * bv;
      }
    }
    #pragma unroll
    for (int j = 0; j < 8; ++j) red[p][c][j] = acc[j];
    __syncthreads();
    if (p == 0){
      #pragma unroll
      for (int j = 0; j < 8; ++j){
        int kk = kc * 8 + j;
        if (kk < 68){
          float s = 0.f;
          #pragma unroll
          for (int pp = 0; pp < 16; ++pp) s += red[pp][c][j];
          atomicAdd(&PTf[(h * KP + kk) * 64 + c], s);
        }
      }
    }
  } else if (bz < 352){
    if (t >= 256) return;                               // whole-wave exit
    __shared__ float nsT[64][65];
    __shared__ float cst[3][64];
    int idx0 = bz - 288, b = idx0 >> 4, m0 = (idx0 & 15) * 64;
    #pragma unroll
    for (int it = 0; it < 16; ++it){
      int idx = it * 256 + t;
      int c = idx >> 6, mm = idx & 63;
      nsT[mm][c] = ns[(b * 64 + c) * NN + m0 + mm];     // coalesced over mm
    }
    if (t < 192){
      int j = t >> 6, mm = t & 63;
      cst[j][mm] = coord[(b * 3 + j) * NN + m0 + mm];
    }
    __syncthreads();
    #pragma unroll
    for (int it = 0; it < 24; ++it){
      int idx = it * 256 + t;                           // 64*96 = 6144
      int mm = idx / KP, kk = idx - mm * KP;
      float v = (kk < 64) ? nsT[mm][kk]
              : (kk < 67) ? cst[kk - 64][mm]
              : (kk == 67) ? 1.f : 0.f;
      Bm[(b * NN + m0 + mm) * KP + kk] = f2bf(v);
    }
  } else {
    if (t >= 256) return;                               // whole-wave exit
    int o0 = (bz - 352) * 64;
    #pragma unroll
    for (int it = 0; it < 24; ++it){
      int idx = it * 256 + t;
      int r = idx / KP, kk = idx - r * KP;
      int o = o0 + r;
      float v = (kk < 64) ? Wv[o * 64 + kk]
              : (kk < 67) ? Wlv[o * 3 + (kk - 64)]
              : (kk == 67) ? blv[o] : 0.f;
      Vm[o * KP + kk] = f2bf(v);
    }
  }
}

// ---------------- K2: fused attention, P held in registers ----------------
// Per WG: (b,h, 32-row n-block), 4 waves; wave owns an m/d QUARTER (256).
// Pass-2 lane mapping (i=q*4+r, j=ln) at d-chunk ds equals pass-1's at
// m-chunk ms=ds -> each lane's attention weights in pass 2 are exactly the
// exp values it computed in pass 1; kept packed bf16 in 64 VGPRs.
__global__ __launch_bounds__(256) void attn_main(
    const float* __restrict__ xs, const float* __restrict__ PTf,
    const short* __restrict__ Bmat, const short* __restrict__ Vm,
    float* __restrict__ out){
  __shared__ short xsL[64 * 32];        // bf16 [c][n_local]  (4 KB)
  __shared__ short AL[32 * LSTR];       // bf16 A rows [n_local][kk] (6.5 KB)
  __shared__ float redS[32 * 4];        // per-row partial sums x 4 waves
  const int t = threadIdx.x, w = t >> 6, lane = t & 63;
  const int q = lane >> 4, ln = lane & 15;
  const int blk = blockIdx.x, nb = blk & 31, bh = blk >> 5;
  const int b = bh >> 3, h = bh & 7;
  const int n0 = nb * 32;

  // ---- stage xs[b][0..63][n0..n0+31] as bf16 ----
  const float* xsb = xs + b * 64 * NN;
  #pragma unroll
  for (int it = 0; it < 2; ++it){
    int idx = it * 256 + t;                     // 512 float4 units
    int c = idx >> 3, nn4 = (idx & 7) << 2;
    f32x4 v = *(const f32x4*)(xsb + c * NN + n0 + nn4);
    short4v pk;
    #pragma unroll
    for (int j = 0; j < 4; ++j) pk[j] = f2bf(v[j]);
    *(short4v*)(&xsL[c * 32 + nn4]) = pk;
  }
  __syncthreads();

  // ---- build A rows via MFMA: A = xs^T . PT^T ----
  // wave w: row-half rh = w&1, kt in {w>>1, w>>1+2, w>>1+4}
  const int rh = w & 1;
  short8 xf0, xf1;
  #pragma unroll
  for (int j = 0; j < 8; ++j){
    xf0[j] = xsL[(q * 8 + j) * 32 + rh * 16 + ln];
    xf1[j] = xsL[(32 + q * 8 + j) * 32 + rh * 16 + ln];
  }
  const float* PTh = PTf + h * KP * 64;
  #pragma unroll
  for (int jt = 0; jt < 3; ++jt){
    int kt = (w >> 1) + 2 * jt;
    const float* pr = PTh + (kt * 16 + ln) * 64;
    f32x4 pa = *(const f32x4*)(pr + q * 8);
    f32x4 pb = *(const f32x4*)(pr + q * 8 + 4);
    f32x4 pc = *(const f32x4*)(pr + 32 + q * 8);
    f32x4 pd = *(const f32x4*)(pr + 32 + q * 8 + 4);
    short8 p0, p1;
    #pragma unroll
    for (int j = 0; j < 4; ++j){
      p0[j] = f2bf(pa[j]); p0[4 + j] = f2bf(pb[j]);
      p1[j] = f2bf(pc[j]); p1[4 + j] = f2bf(pd[j]);
    }
    f32x4 a = {0.f, 0.f, 0.f, 0.f};
    a = __builtin_amdgcn_mfma_f32_16x16x32_bf16(xf0, p0, a, 0, 0, 0);
    a = __builtin_amdgcn_mfma_f32_16x16x32_bf16(xf1, p1, a, 0, 0, 0);
    #pragma unroll
    for (int r = 0; r < 4; ++r)
      AL[(rh * 16 + q * 4 + r) * LSTR + kt * 16 + ln] = f2bf(a[r]);
  }
  __syncthreads();

  // ---- persistent fragments: all 32 rows ----
  short8 af[2][3], bn[2][3];
  const short* Bb = Bmat + b * NN * KP;
  #pragma unroll
  for (int rf = 0; rf < 2; ++rf){
    #pragma unroll
    for (int s = 0; s < 3; ++s){
      af[rf][s] = *(const short8*)(&AL[(rf * 16 + ln) * LSTR + s * 32 + q * 8]);
      bn[rf][s] = *(const short8*)(Bb + (n0 + rf * 16 + ln) * KP + s * 32 + q * 8);
    }
  }
  const float KEXP = 0.045084220f;   // log2(e)/32  (SCALE = sqrt(1024) = 32)

  // ---- pass 1: wave's m-quarter; keep exp values packed in registers ----
  float sum[2][4];
  #pragma unroll
  for (int rf = 0; rf < 2; ++rf)
    #pragma unroll
    for (int r = 0; r < 4; ++r) sum[rf][r] = 0.f;
  unsigned pw[2][4][8];              // packed bf16 pairs over ms

  #pragma unroll
  for (int ms = 0; ms < 16; ++ms){
    const short* bp = Bb + (w * 256 + ms * 16 + ln) * KP + q * 8;
    short8 bf0 = *(const short8*)(bp);
    short8 bf1 = *(const short8*)(bp + 32);
    short8 bf2 = *(const short8*)(bp + 64);
    #pragma unroll
    for (int rf = 0; rf < 2; ++rf){
      f32x4 e = {0.f, 0.f, 0.f, 0.f};
      e = __builtin_amdgcn_mfma_f32_16x16x32_bf16(af[rf][0], bf0, e, 0, 0, 0);
      e = __builtin_amdgcn_mfma_f32_16x16x32_bf16(af[rf][1], bf1, e, 0, 0, 0);
      e = __builtin_amdgcn_mfma_f32_16x16x32_bf16(af[rf][2], bf2, e, 0, 0, 0);
      #pragma unroll
      for (int r = 0; r < 4; ++r){
        float pe = __builtin_amdgcn_exp2f(e[r] * KEXP);
        sum[rf][r] += pe;
        unsigned hb = (unsigned)(unsigned short)f2bf(pe);
        if (ms & 1) pw[rf][r][ms >> 1] |= hb << 16;
        else        pw[rf][r][ms >> 1]  = hb;
      }
    }
  }
  // reduce over the 16 m-columns (ln bits), then across waves via LDS
  #pragma unroll
  for (int rf = 0; rf < 2; ++rf){
    #pragma unroll
    for (int r = 0; r < 4; ++r){
      float s = sum[rf][r];
      s += __shfl_xor(s, 1); s += __shfl_xor(s, 2);
      s += __shfl_xor(s, 4); s += __shfl_xor(s, 8);
      if (ln == 0) redS[(rf * 16 + q * 4 + r) * 4 + w] = s;
    }
  }
  __syncthreads();
  float rinv[2][4];
  #pragma unroll
  for (int rf = 0; rf < 2; ++rf){
    #pragma unroll
    for (int r = 0; r < 4; ++r){
      f32x4 v4 = *(const f32x4*)(&redS[(rf * 16 + q * 4 + r) * 4]);
      rinv[rf][r] = 1.0f / (v4[0] + v4[1] + v4[2] + v4[3]);
    }
  }

  // ---- pass 2: wave's d-quarter: vc GEMM + cached P + store ----
  float* outp = out + (size_t)bh * (1024 * 1024);
  const short* Vh = Vm + h * 1024 * KP;
  #pragma unroll
  for (int ds = 0; ds < 16; ++ds){
    const short* vp = Vh + (w * 256 + ds * 16 + ln) * KP + q * 8;
    short8 vf0 = *(const short8*)(vp);
    short8 vf1 = *(const short8*)(vp + 32);
    short8 vf2 = *(const short8*)(vp + 64);
    #pragma unroll
    for (int rf = 0; rf < 2; ++rf){
      f32x4 vv = {0.f, 0.f, 0.f, 0.f};
      vv = __builtin_amdgcn_mfma_f32_16x16x32_bf16(bn[rf][0], vf0, vv, 0, 0, 0);
      vv = __builtin_amdgcn_mfma_f32_16x16x32_bf16(bn[rf][1], vf1, vv, 0, 0, 0);
      vv = __builtin_amdgcn_mfma_f32_16x16x32_bf16(bn[rf][2], vf2, vv, 0, 0, 0);
      f32x4 o;
      #pragma unroll
      for (int r = 0; r < 4; ++r){
        unsigned u = pw[rf][r][ds >> 1];
        float pf = __builtin_bit_cast(float,
            (ds & 1) ? (u & 0xFFFF0000u) : (u << 16));
        o[r] = pf * rinv[rf][r] * vv[r];
      }
      // out[((b*8+h)*1024 + d)*1024 + n]
      *(f32x4*)(outp + (w * 256 + ds * 16 + ln) * NN + n0 + rf * 16 + q * 4) = o;
    }
  }
}

extern "C" void kernel_launch(void* const* d_in, const int* in_sizes, int n_in,
                              void* d_out, int out_size, void* d_ws, size_t ws_size,
                              hipStream_t stream){
  const float* coord = (const float*)d_in[0];
  const float* x     = (const float*)d_in[1];
  const float* nbr   = (const float*)d_in[2];
  const float* Wq    = (const float*)d_in[3];
  const float* Wk    = (const float*)d_in[4];
  const float* Wv    = (const float*)d_in[5];
  const float* Wlq   = (const float*)d_in[6];
  const float* blq   = (const float*)d_in[7];
  const float* Wlv   = (const float*)d_in[8];
  const float* blv   = (const float*)d_in[9];
  float* out = (float*)d_out;

  char* ws = (char*)d_ws;
  float* PTf = (float*)ws;                        // 8*96*64*4   =  196608 B
  short* Bm  = (short*)(ws + 196608);             // 4*1024*96*2 =  786432 B
  short* Vm  = (short*)(ws + 196608 + 786432);    // 8*1024*96*2 = 1572864 B
  // total ws: 2,555,904 B

  hipMemsetAsync(PTf, 0, 196608, stream);
  prep_all<<<480, 1024, 0, stream>>>(Wq, Wk, Wlq, blq, Wv, Wlv, blv, nbr, coord,
                                     PTf, Bm, Vm);
  attn_main<<<1024, 256, 0, stream>>>(x, PTf, Bm, Vm, out);
}